// Round 10
// baseline (6265.852 us; speedup 1.0000x reference)
//
#include <hip/hip_runtime.h>
#include <math.h>
#include <float.h>

// Problem dims: B=256, N=100, D=512, H=8, HD=64, DFF=2048
#define TOKS 25600
#define DMODEL 512
#define SEQ 100

#define TILE 64
#define BKK 16

// Finite stand-in for -inf. MUST be bf16-representable (|v| < 3.3895e38):
// -FLT_MAX rounds to -inf in bf16 -> (-inf)-(-inf)=NaN in the comparator
// (this was the R4-R8 failure). -1e38 is finite in fp32 AND bf16.
#define MASKED_VAL (-1e38f)

// clamp to [-1e38, 1e38]; NaN -> -1e38 (fmaxf(NaN,x)=x per IEEE).
__device__ __forceinline__ float clamp_finite(float v) {
    return fminf(fmaxf(v, -1e38f), 1e38f);
}

// ---------------------------------------------------------------------------
// Generic fp32 tiled GEMM: C[m][n] (+)= alpha * sum_k A[m][k]*W'[n][k] + bias[n]
//   TRANS_W=false: W'[n][k] = W[n*ldw + k]
//   TRANS_W=true : W'[n][k] = W[k*ldw + n]
// ACCUM=true: C += result (bias should be nullptr on the accumulating pass).
// Optional ReLU; optional pos-emb add (pos[(m%100)*N + n]).
// Batched via blockIdx.z: off = (z/bdiv)*s1 + (z%bdiv)*s2 for A, W, C.
// ---------------------------------------------------------------------------
template<bool RELU, bool TRANS_W, bool ADD_POS, bool ACCUM>
__global__ __launch_bounds__(256) void gemm_k(
    const float* __restrict__ A, const float* __restrict__ W,
    const float* __restrict__ bias, const float* __restrict__ pos,
    float* __restrict__ C,
    int M, int N, int K, int lda, int ldw, int ldc,
    int bdiv, long long sA1, long long sA2, long long sW1, long long sW2,
    long long sC1, long long sC2, float alpha)
{
    __shared__ __align__(16) float As[BKK][TILE];
    __shared__ __align__(16) float Ws[BKK][TILE];

    int z = blockIdx.z;
    A += (size_t)((long long)(z / bdiv) * sA1 + (long long)(z % bdiv) * sA2);
    W += (size_t)((long long)(z / bdiv) * sW1 + (long long)(z % bdiv) * sW2);
    C += (size_t)((long long)(z / bdiv) * sC1 + (long long)(z % bdiv) * sC2);

    int m0 = blockIdx.y * TILE;
    int n0 = blockIdx.x * TILE;
    int tid = threadIdx.x;
    int tm = tid >> 4;   // 0..15 row group
    int tn = tid & 15;   // 0..15 col group (consecutive lanes -> coalesced C)

    float acc[4][4] = {};

    int lr = tid >> 2;        // 0..63 tile row for loads
    int lk = (tid & 3) * 4;   // 0,4,8,12 k-start for loads

    for (int k0 = 0; k0 < K; k0 += BKK) {
        {   // A tile -> As[kk][m] (transposed)
            int gm = m0 + lr;
            float v[4];
#pragma unroll
            for (int j = 0; j < 4; ++j) {
                int gk = k0 + lk + j;
                v[j] = (gm < M && gk < K) ? A[(long long)gm * lda + gk] : 0.f;
            }
#pragma unroll
            for (int j = 0; j < 4; ++j) As[lk + j][lr] = v[j];
        }
        if (TRANS_W) {  // W tile rows=k, cols=n
            int kk = tid >> 4;
            int nc = (tid & 15) * 4;
            int gk = k0 + kk;
#pragma unroll
            for (int j = 0; j < 4; ++j) {
                int gn = n0 + nc + j;
                Ws[kk][nc + j] = (gk < K && gn < N) ? W[(long long)gk * ldw + gn] : 0.f;
            }
        } else {        // W tile rows=n, cols=k -> Ws[kk][n]
            int gn = n0 + lr;
            float v[4];
#pragma unroll
            for (int j = 0; j < 4; ++j) {
                int gk = k0 + lk + j;
                v[j] = (gn < N && gk < K) ? W[(long long)gn * ldw + gk] : 0.f;
            }
#pragma unroll
            for (int j = 0; j < 4; ++j) Ws[lk + j][lr] = v[j];
        }
        __syncthreads();
#pragma unroll
        for (int kk = 0; kk < BKK; ++kk) {
            float4 a4 = *(const float4*)&As[kk][tm * 4];
            float4 w4 = *(const float4*)&Ws[kk][tn * 4];
            float av[4] = {a4.x, a4.y, a4.z, a4.w};
            float wv[4] = {w4.x, w4.y, w4.z, w4.w};
#pragma unroll
            for (int i = 0; i < 4; ++i)
#pragma unroll
                for (int j = 0; j < 4; ++j) acc[i][j] += av[i] * wv[j];
        }
        __syncthreads();
    }

#pragma unroll
    for (int i = 0; i < 4; ++i) {
        int gm = m0 + tm * 4 + i;
        if (gm >= M) continue;
        const float* posrow = nullptr;
        if (ADD_POS) posrow = pos + (long long)(gm % 100) * N;
#pragma unroll
        for (int j = 0; j < 4; ++j) {
            int gn = n0 + tn * 4 + j;
            if (gn >= N) continue;
            float v = acc[i][j] * alpha;
            if (bias) v += bias[gn];
            if (ADD_POS) v += posrow[gn];
            if (RELU) v = fmaxf(v, 0.f);
            long long ci = (long long)gm * ldc + gn;
            if (ACCUM) v += C[ci];
            C[ci] = v;
        }
    }
}

// h1[tok][j] = relu(x[tok]*w1[j] + b1[j])  (tok relative to chunk)
__global__ __launch_bounds__(256) void embed_h1(
    const float* __restrict__ x, const float* __restrict__ w1,
    const float* __restrict__ b1, float* __restrict__ h1)
{
    int idx = blockIdx.x * 256 + threadIdx.x;
    int tok = idx >> 8;
    int j = idx & 255;
    float v = x[tok] * w1[j] + b1[j];
    h1[idx] = fmaxf(v, 0.f);
}

// Row softmax over rows of length 100 (in place). One wave per row.
__global__ __launch_bounds__(256) void softmax_rows(float* __restrict__ S, int nrows)
{
    int row = blockIdx.x * 4 + (threadIdx.x >> 6);
    if (row >= nrows) return;
    int lane = threadIdx.x & 63;
    float* p = S + (long long)row * SEQ;
    float x0 = p[lane];
    float x1 = (lane + 64 < SEQ) ? p[lane + 64] : -INFINITY;
    float m = fmaxf(x0, x1);
#pragma unroll
    for (int off = 32; off; off >>= 1) m = fmaxf(m, __shfl_xor(m, off, 64));
    float e0 = __expf(x0 - m);
    float e1 = (lane + 64 < SEQ) ? __expf(x1 - m) : 0.f;
    float s = e0 + e1;
#pragma unroll
    for (int off = 32; off; off >>= 1) s += __shfl_xor(s, off, 64);
    float inv = 1.f / s;
    p[lane] = e0 * inv;
    if (lane + 64 < SEQ) p[lane + 64] = e1 * inv;
}

// out[tok] = LN(a[tok] + r[tok]) * g + b   (rows of 512)
__global__ __launch_bounds__(256) void add_ln(
    const float* __restrict__ a, const float* __restrict__ r,
    const float* __restrict__ g, const float* __restrict__ bb,
    float* __restrict__ out)
{
    int tok = blockIdx.x;
    int tid = threadIdx.x;
    const float* pa = a + (long long)tok * DMODEL;
    const float* pr = r + (long long)tok * DMODEL;
    float v0 = pa[tid] + pr[tid];
    float v1 = pa[tid + 256] + pr[tid + 256];
    float s = v0 + v1;
    float q = v0 * v0 + v1 * v1;
    __shared__ float reds[4], redq[4];
#pragma unroll
    for (int off = 32; off; off >>= 1) {
        s += __shfl_xor(s, off, 64);
        q += __shfl_xor(q, off, 64);
    }
    int wid = tid >> 6;
    if ((tid & 63) == 0) { reds[wid] = s; redq[wid] = q; }
    __syncthreads();
    s = reds[0] + reds[1] + reds[2] + reds[3];
    q = redq[0] + redq[1] + redq[2] + redq[3];
    float mean = s * (1.f / DMODEL);
    float var = q * (1.f / DMODEL) - mean * mean;
    float rs = rsqrtf(var + 1e-5f);
    float* po = out + (long long)tok * DMODEL;
    po[tid]       = (v0 - mean) * rs * g[tid]       + bb[tid];
    po[tid + 256] = (v1 - mean) * rs * g[tid + 256] + bb[tid + 256];
}

// ---------------------------------------------------------------------------
// Decode v5 (GREEN in R9; only ldb/out indexing generalized for per-chunk use):
// 128 threads/block, one block per (local) batch. Thread s holds column s in
// a register array (coalesced prefetch, clamped finite); per-step shfl reduce
// + rv/ri LDS + 2 barriers; per-thread 'alive' register mask. Every store is
// clamped to [-1e38,1e38]. First-occurrence tie-break preserved.
// base[t*ldb + blockIdx.x*100 + s]; out[blockIdx.x*10000 + t*100 + s]
// ---------------------------------------------------------------------------
__global__ __launch_bounds__(128) void decode5_k(
    const float* __restrict__ base, float* __restrict__ out, int ldb)
{
    __shared__ float rv[2];
    __shared__ int ri[2];
    __shared__ int win;
    int b = blockIdx.x;
    int s = threadIdx.x;

    float p[SEQ];
#pragma unroll
    for (int t = 0; t < SEQ; ++t) {
        float v = (s < SEQ) ? base[(long long)t * ldb + b * SEQ + s] : MASKED_VAL;
        p[t] = clamp_finite(v);
    }
    bool alive = true;

    float* po = out + (long long)b * (SEQ * SEQ);
#pragma unroll
    for (int t = 0; t < SEQ; ++t) {
        float val = (s < SEQ && alive) ? p[t] : MASKED_VAL;
        if (s < SEQ) po[t * SEQ + s] = val;
        float v = val;
        int ii = s;
#pragma unroll
        for (int off = 32; off; off >>= 1) {
            float ov = __shfl_down(v, off, 64);
            int oi = __shfl_down(ii, off, 64);
            if (ov > v || (ov == v && oi < ii)) { v = ov; ii = oi; }
        }
        int wid = s >> 6;
        if ((s & 63) == 0) { rv[wid] = v; ri[wid] = ii; }
        __syncthreads();
        if (s == 0) {
            float v0 = rv[0], v1 = rv[1];
            int i0 = ri[0], i1 = ri[1];
            win = (v1 > v0 || (v1 == v0 && i1 < i0)) ? i1 : i0;
        }
        __syncthreads();
        if (win == s) alive = false;
    }
}

extern "C" void kernel_launch(void* const* d_in, const int* in_sizes, int n_in,
                              void* d_out, int out_size, void* d_ws, size_t ws_size,
                              hipStream_t stream)
{
    const float* x          = (const float*)d_in[0];
    const float* ve_w1      = (const float*)d_in[1];
    const float* ve_b1      = (const float*)d_in[2];
    const float* ve_w2      = (const float*)d_in[3];
    const float* ve_b2      = (const float*)d_in[4];
    const float* pos_emb    = (const float*)d_in[5];
    const float* attn_in_w  = (const float*)d_in[6];
    const float* attn_in_b  = (const float*)d_in[7];
    const float* attn_out_w = (const float*)d_in[8];
    const float* attn_out_b = (const float*)d_in[9];
    const float* ffn_w1     = (const float*)d_in[10];
    const float* ffn_b1     = (const float*)d_in[11];
    const float* ffn_w2     = (const float*)d_in[12];
    const float* ffn_b2     = (const float*)d_in[13];
    const float* ln1_g      = (const float*)d_in[14];
    const float* ln1_b      = (const float*)d_in[15];
    const float* ln2_g      = (const float*)d_in[16];
    const float* ln2_b      = (const float*)d_in[17];
    const float* rank_emb   = (const float*)d_in[18];
    const float* qp_w       = (const float*)d_in[19];
    const float* qp_b       = (const float*)d_in[20];
    const float* kp_w       = (const float*)d_in[21];
    const float* kp_b       = (const float*)d_in[22];
    float* outp             = (float*)d_out;

    // ---- workspace plan ----
    // Persistent: qdec [100,512] (0.2MB). Per-chunk (T = CB*100 tokens):
    //   rb base_chunk [100, T]  : T*100 floats (decode runs per chunk!)
    //   r0 h -> z               : T*512
    //   r1 qkv -> ffn mid-half  : T*1536   (ffn split along DFF, ACCUM 2nd half)
    //   r2 h1/S/tmp/tmp2/kdec   : T*800
    //   r3 ao -> h2             : T*512
    // total per token: 3460 floats (13.84KB) -> CB=8 fits in ~11.3MB.
    const size_t GUARD = 4096;
    const int plans[] = {256, 128, 64, 32, 16, 8, 4, 2, 1};
    int CB = 0;
    for (int i = 0; i < 9; ++i) {
        long long T = plans[i] * 100LL;
        size_t need = 204800 + GUARD + (size_t)(T * 3460LL) * 4 + 5 * GUARD;
        if (need <= ws_size) { CB = plans[i]; break; }
    }
    if (CB == 0) return;

    const long long T = CB * 100LL;
    char* ws = (char*)d_ws;
    float* qdec = (float*)ws;                              // [100,512]
    float* rb   = (float*)(ws + 204800 + GUARD);           // [100, T]
    float* r0   = rb + T * 100 + GUARD / 4;                // h, later z
    float* r1   = r0 + T * 512 + GUARD / 4;                // qkv, later mid-half
    float* r2   = r1 + T * 1536 + GUARD / 4;               // h1/S/tmp/tmp2/kdec
    float* r3   = r2 + T * 800 + GUARD / 4;                // ao, later h2
    const long long Z = 0;
    const int gy = (int)((T + 63) / 64);
    const int nchunk = 256 / CB;

    // q_dec = rank_emb @ qp_w^T + qp_b   (M=100,N=512,K=512)
    gemm_k<false, false, false, false><<<dim3(8, 2, 1), 256, 0, stream>>>(
        rank_emb, qp_w, qp_b, nullptr, qdec,
        100, 512, 512, 512, 512, 512, 1, Z, Z, Z, Z, Z, Z, 1.f);

    for (int c = 0; c < nchunk; ++c) {
        const long long tok0 = (long long)c * T;

        // 1) h1 = relu(x*w1+b1) -> r2 [T,256]
        embed_h1<<<dim3((unsigned)T), dim3(256), 0, stream>>>(x + tok0, ve_w1, ve_b1, r2);

        // 2) h = h1 @ ve_w2^T + ve_b2 + pos -> r0   (M=T,N=512,K=256)
        gemm_k<false, false, true, false><<<dim3(8, gy, 1), 256, 0, stream>>>(
            r2, ve_w2, ve_b2, pos_emb, r0,
            (int)T, 512, 256, 256, 256, 512, 1, Z, Z, Z, Z, Z, Z, 1.f);

        // 3) qkv = h @ attn_in_w^T + attn_in_b -> r1   (M=T,N=1536,K=512)
        gemm_k<false, false, false, false><<<dim3(24, gy, 1), 256, 0, stream>>>(
            r0, attn_in_w, attn_in_b, nullptr, r1,
            (int)T, 1536, 512, 512, 512, 1536, 1, Z, Z, Z, Z, Z, Z, 1.f);

        // 4) S = (Q @ K^T)/8, batched over CB*8 -> r2   (M=100,N=100,K=64)
        gemm_k<false, false, false, false><<<dim3(2, 2, CB * 8), 256, 0, stream>>>(
            r1, r1 + 512, nullptr, nullptr, r2,
            100, 100, 64, 1536, 1536, 100,
            8, 153600LL, 64LL, 153600LL, 64LL, 80000LL, 10000LL, 0.125f);

        // 5) softmax rows of S  (T*8 rows)
        softmax_rows<<<dim3((unsigned)((T * 8 + 3) / 4)), dim3(256), 0, stream>>>(r2, (int)(T * 8));

        // 6) ao = P @ V, batched -> r3   (M=100,N=64,K=100)
        gemm_k<false, true, false, false><<<dim3(1, 2, CB * 8), 256, 0, stream>>>(
            r2, r1 + 1024, nullptr, nullptr, r3,
            100, 64, 100, 100, 1536, 512,
            8, 80000LL, 10000LL, 153600LL, 64LL, 51200LL, 64LL, 1.f);

        // 7) tmp = ao @ attn_out_w^T + attn_out_b -> r2   (M=T,N=512,K=512)
        gemm_k<false, false, false, false><<<dim3(8, gy, 1), 256, 0, stream>>>(
            r3, attn_out_w, attn_out_b, nullptr, r2,
            (int)T, 512, 512, 512, 512, 512, 1, Z, Z, Z, Z, Z, Z, 1.f);

        // 8) h2 = LN(h + tmp) -> r3
        add_ln<<<dim3((unsigned)T), dim3(256), 0, stream>>>(r0, r2, ln1_g, ln1_b, r3);

        // 9a) mid_a = relu(h2 @ W1[0:1024]^T + b1a) -> r1 [T,1024]
        gemm_k<true, false, false, false><<<dim3(16, gy, 1), 256, 0, stream>>>(
            r3, ffn_w1, ffn_b1, nullptr, r1,
            (int)T, 1024, 512, 512, 512, 1024, 1, Z, Z, Z, Z, Z, Z, 1.f);

        // 9b) tmp2 = mid_a @ W2[:,0:1024]^T + b2 -> r2   (K=1024)
        gemm_k<false, false, false, false><<<dim3(8, gy, 1), 256, 0, stream>>>(
            r1, ffn_w2, ffn_b2, nullptr, r2,
            (int)T, 512, 1024, 1024, 2048, 512, 1, Z, Z, Z, Z, Z, Z, 1.f);

        // 9c) mid_b = relu(h2 @ W1[1024:2048]^T + b1b) -> r1 [T,1024]
        gemm_k<true, false, false, false><<<dim3(16, gy, 1), 256, 0, stream>>>(
            r3, ffn_w1 + 1024 * 512, ffn_b1 + 1024, nullptr, r1,
            (int)T, 1024, 512, 512, 512, 1024, 1, Z, Z, Z, Z, Z, Z, 1.f);

        // 9d) tmp2 += mid_b @ W2[:,1024:2048]^T   (ACCUM, no bias)
        gemm_k<false, false, false, true><<<dim3(8, gy, 1), 256, 0, stream>>>(
            r1, ffn_w2 + 1024, nullptr, nullptr, r2,
            (int)T, 512, 1024, 1024, 2048, 512, 1, Z, Z, Z, Z, Z, Z, 1.f);

        // 10) z = LN(h2 + tmp2) -> r0
        add_ln<<<dim3((unsigned)T), dim3(256), 0, stream>>>(r3, r2, ln2_g, ln2_b, r0);

        // 11) k_dec = z @ kp_w^T + kp_b -> r2   (M=T,N=512,K=512)
        gemm_k<false, false, false, false><<<dim3(8, gy, 1), 256, 0, stream>>>(
            r0, kp_w, kp_b, nullptr, r2,
            (int)T, 512, 512, 512, 512, 512, 1, Z, Z, Z, Z, Z, Z, 1.f);

        // 12) base_chunk = q_dec @ k_dec^T -> rb   (M=100,N=T,K=512, ldc=T)
        gemm_k<false, false, false, false><<<dim3(gy, 2, 1), 256, 0, stream>>>(
            qdec, r2, nullptr, nullptr, rb,
            100, (int)T, 512, 512, 512, (int)T, 1, Z, Z, Z, Z, Z, Z, 1.f);

        // 13) decode this chunk's batches -> d_out
        decode5_k<<<dim3(CB), dim3(128), 0, stream>>>(
            rb, outp + (long long)c * CB * (SEQ * SEQ), (int)T);
    }
}

// Round 11
// 2326.525 us; speedup vs baseline: 2.6932x; 2.6932x over previous
//
#include <hip/hip_runtime.h>
#include <math.h>
#include <float.h>

// Problem dims: B=256, N=100, D=512, H=8, HD=64, DFF=2048
#define TOKS 25600
#define DMODEL 512
#define SEQ 100

#define TILE 64
#define BKK 16

// Finite stand-in for -inf. MUST be bf16-representable (|v| < 3.3895e38):
// -FLT_MAX rounds to -inf in bf16 -> (-inf)-(-inf)=NaN in the comparator
// (this was the R4-R8 failure). -1e38 is finite in fp32 AND bf16.
#define MASKED_VAL (-1e38f)

// clamp to [-1e38, 1e38]; NaN -> -1e38 (fmaxf(NaN,x)=x per IEEE).
__device__ __forceinline__ float clamp_finite(float v) {
    return fminf(fmaxf(v, -1e38f), 1e38f);
}

// fp32 -> bf16 (round to nearest even)
__device__ __forceinline__ short f2bf(float f) {
    unsigned u = __float_as_uint(f);
    u += 0x7FFFu + ((u >> 16) & 1u);
    return (short)(u >> 16);
}

typedef __attribute__((ext_vector_type(8))) short bf16x8;
typedef __attribute__((ext_vector_type(4))) float f32x4;

// ---------------------------------------------------------------------------
// MFMA bf16 GEMM: C[m][n] (+)= sum_k A[m][k]*W[n][k] + bias[n] (+pos) (relu)
// A fp32 [M][lda]; W fp32 [N][ldw] (row-major weight = B^T); C fp32 [M][ldc].
// 128x128 tile, 256 threads = 4 waves (2x2), wave tile 64x64 = 4x4 frags of
// 16x16 via v_mfma_f32_16x16x32_bf16. fp32 staged->bf16 in LDS (rows padded
// to 40 bf16 -> 2-way bank aliasing only). K must be a multiple of 32.
// Fragment maps (m89/m92-verified): A: lane l holds A[m=l&15][k=(l>>4)*8+j];
// B: lane l holds B[k=(l>>4)*8+j][n=l&15] (stored as W[n][k] rows);
// C/D: col n = l&15, row m = (l>>4)*4 + reg.
// ---------------------------------------------------------------------------
#define MT 128
#define KT 32
#define LDT 40

template<bool RELU, bool ADD_POS, bool ACCUM>
__global__ __launch_bounds__(256) void gemm_mfma(
    const float* __restrict__ A, const float* __restrict__ W,
    const float* __restrict__ bias, const float* __restrict__ pos,
    float* __restrict__ C,
    int M, int N, int K, int lda, int ldw, int ldc)
{
    __shared__ short As[MT * LDT];
    __shared__ short Bs[MT * LDT];
    int m0 = blockIdx.y * MT;
    int n0 = blockIdx.x * MT;
    int tid = threadIdx.x;
    int lane = tid & 63;
    int wave = tid >> 6;
    int wm = (wave >> 1) * 64;   // wave row offset in tile
    int wn = (wave & 1) * 64;    // wave col offset in tile
    int lr = lane >> 4;          // 0..3
    int lc = lane & 15;          // 0..15

    f32x4 acc[4][4] = {};

    for (int k0 = 0; k0 < K; k0 += KT) {
        // stage A and W tiles (128 rows x 32 k) as bf16; coalesced float4 loads
#pragma unroll
        for (int i = 0; i < 4; ++i) {
            int linear = i * 256 + tid;      // 0..1023
            int row = linear >> 3;           // 0..127
            int f4 = (linear & 7) * 4;       // 0,4,..,28
            {
                int gm = m0 + row;
                float4 v = make_float4(0.f, 0.f, 0.f, 0.f);
                if (gm < M) v = *(const float4*)&A[(long long)gm * lda + k0 + f4];
                short* d = &As[row * LDT + f4];
                d[0] = f2bf(v.x); d[1] = f2bf(v.y); d[2] = f2bf(v.z); d[3] = f2bf(v.w);
            }
            {
                int gn = n0 + row;
                float4 v = make_float4(0.f, 0.f, 0.f, 0.f);
                if (gn < N) v = *(const float4*)&W[(long long)gn * ldw + k0 + f4];
                short* d = &Bs[row * LDT + f4];
                d[0] = f2bf(v.x); d[1] = f2bf(v.y); d[2] = f2bf(v.z); d[3] = f2bf(v.w);
            }
        }
        __syncthreads();
        bf16x8 af[4], bfr[4];
#pragma unroll
        for (int i = 0; i < 4; ++i) {
            af[i]  = *(const bf16x8*)&As[(wm + i * 16 + lc) * LDT + lr * 8];
            bfr[i] = *(const bf16x8*)&Bs[(wn + i * 16 + lc) * LDT + lr * 8];
        }
#pragma unroll
        for (int i = 0; i < 4; ++i)
#pragma unroll
            for (int j = 0; j < 4; ++j)
                acc[i][j] = __builtin_amdgcn_mfma_f32_16x16x32_bf16(
                    af[i], bfr[j], acc[i][j], 0, 0, 0);
        __syncthreads();
    }

#pragma unroll
    for (int i = 0; i < 4; ++i) {
#pragma unroll
        for (int j = 0; j < 4; ++j) {
#pragma unroll
            for (int r = 0; r < 4; ++r) {
                int gm = m0 + wm + i * 16 + lr * 4 + r;
                int gn = n0 + wn + j * 16 + lc;
                if (gm < M && gn < N) {
                    float v = acc[i][j][r];
                    if (bias) v += bias[gn];
                    if (ADD_POS) v += pos[(long long)(gm % 100) * N + gn];
                    if (RELU) v = fmaxf(v, 0.f);
                    long long ci = (long long)gm * ldc + gn;
                    if (ACCUM) v += C[ci];
                    C[ci] = v;
                }
            }
        }
    }
}

// ---------------------------------------------------------------------------
// fp32 tiled GEMM (kept for skinny/batched shapes: qdec, S, ao, base).
// DECODE_LAYOUT: C index = (gn/100)*10000 + gm*100 + (gn%100) (base->d_out).
// ---------------------------------------------------------------------------
template<bool RELU, bool TRANS_W, bool ADD_POS, bool ACCUM, bool DECODE_LAYOUT>
__global__ __launch_bounds__(256) void gemm_k(
    const float* __restrict__ A, const float* __restrict__ W,
    const float* __restrict__ bias, const float* __restrict__ pos,
    float* __restrict__ C,
    int M, int N, int K, int lda, int ldw, int ldc,
    int bdiv, long long sA1, long long sA2, long long sW1, long long sW2,
    long long sC1, long long sC2, float alpha)
{
    __shared__ __align__(16) float As[BKK][TILE];
    __shared__ __align__(16) float Ws[BKK][TILE];

    int z = blockIdx.z;
    A += (size_t)((long long)(z / bdiv) * sA1 + (long long)(z % bdiv) * sA2);
    W += (size_t)((long long)(z / bdiv) * sW1 + (long long)(z % bdiv) * sW2);
    C += (size_t)((long long)(z / bdiv) * sC1 + (long long)(z % bdiv) * sC2);

    int m0 = blockIdx.y * TILE;
    int n0 = blockIdx.x * TILE;
    int tid = threadIdx.x;
    int tm = tid >> 4;
    int tn = tid & 15;

    float acc[4][4] = {};

    int lr = tid >> 2;
    int lk = (tid & 3) * 4;

    for (int k0 = 0; k0 < K; k0 += BKK) {
        {
            int gm = m0 + lr;
            float v[4];
#pragma unroll
            for (int j = 0; j < 4; ++j) {
                int gk = k0 + lk + j;
                v[j] = (gm < M && gk < K) ? A[(long long)gm * lda + gk] : 0.f;
            }
#pragma unroll
            for (int j = 0; j < 4; ++j) As[lk + j][lr] = v[j];
        }
        if (TRANS_W) {
            int kk = tid >> 4;
            int nc = (tid & 15) * 4;
            int gk = k0 + kk;
#pragma unroll
            for (int j = 0; j < 4; ++j) {
                int gn = n0 + nc + j;
                Ws[kk][nc + j] = (gk < K && gn < N) ? W[(long long)gk * ldw + gn] : 0.f;
            }
        } else {
            int gn = n0 + lr;
            float v[4];
#pragma unroll
            for (int j = 0; j < 4; ++j) {
                int gk = k0 + lk + j;
                v[j] = (gn < N && gk < K) ? W[(long long)gn * ldw + gk] : 0.f;
            }
#pragma unroll
            for (int j = 0; j < 4; ++j) Ws[lk + j][lr] = v[j];
        }
        __syncthreads();
#pragma unroll
        for (int kk = 0; kk < BKK; ++kk) {
            float4 a4 = *(const float4*)&As[kk][tm * 4];
            float4 w4 = *(const float4*)&Ws[kk][tn * 4];
            float av[4] = {a4.x, a4.y, a4.z, a4.w};
            float wv[4] = {w4.x, w4.y, w4.z, w4.w};
#pragma unroll
            for (int i = 0; i < 4; ++i)
#pragma unroll
                for (int j = 0; j < 4; ++j) acc[i][j] += av[i] * wv[j];
        }
        __syncthreads();
    }

#pragma unroll
    for (int i = 0; i < 4; ++i) {
        int gm = m0 + tm * 4 + i;
        if (gm >= M) continue;
        const float* posrow = nullptr;
        if (ADD_POS) posrow = pos + (long long)(gm % 100) * N;
#pragma unroll
        for (int j = 0; j < 4; ++j) {
            int gn = n0 + tn * 4 + j;
            if (gn >= N) continue;
            float v = acc[i][j] * alpha;
            if (bias) v += bias[gn];
            if (ADD_POS) v += posrow[gn];
            if (RELU) v = fmaxf(v, 0.f);
            long long ci;
            if (DECODE_LAYOUT)
                ci = (long long)(gn / 100) * 10000 + (long long)gm * 100 + (gn % 100);
            else
                ci = (long long)gm * ldc + gn;
            if (ACCUM) v += C[ci];
            C[ci] = v;
        }
    }
}

// h1[tok][j] = relu(x[tok]*w1[j] + b1[j])  (tok relative to chunk)
__global__ __launch_bounds__(256) void embed_h1(
    const float* __restrict__ x, const float* __restrict__ w1,
    const float* __restrict__ b1, float* __restrict__ h1)
{
    int idx = blockIdx.x * 256 + threadIdx.x;
    int tok = idx >> 8;
    int j = idx & 255;
    float v = x[tok] * w1[j] + b1[j];
    h1[idx] = fmaxf(v, 0.f);
}

// Row softmax over rows of length 100 (in place). One wave per row.
__global__ __launch_bounds__(256) void softmax_rows(float* __restrict__ S, int nrows)
{
    int row = blockIdx.x * 4 + (threadIdx.x >> 6);
    if (row >= nrows) return;
    int lane = threadIdx.x & 63;
    float* p = S + (long long)row * SEQ;
    float x0 = p[lane];
    float x1 = (lane + 64 < SEQ) ? p[lane + 64] : -INFINITY;
    float m = fmaxf(x0, x1);
#pragma unroll
    for (int off = 32; off; off >>= 1) m = fmaxf(m, __shfl_xor(m, off, 64));
    float e0 = __expf(x0 - m);
    float e1 = (lane + 64 < SEQ) ? __expf(x1 - m) : 0.f;
    float s = e0 + e1;
#pragma unroll
    for (int off = 32; off; off >>= 1) s += __shfl_xor(s, off, 64);
    float inv = 1.f / s;
    p[lane] = e0 * inv;
    if (lane + 64 < SEQ) p[lane + 64] = e1 * inv;
}

// out[tok] = LN(a[tok] + r[tok]) * g + b   (rows of 512)
__global__ __launch_bounds__(256) void add_ln(
    const float* __restrict__ a, const float* __restrict__ r,
    const float* __restrict__ g, const float* __restrict__ bb,
    float* __restrict__ out)
{
    int tok = blockIdx.x;
    int tid = threadIdx.x;
    const float* pa = a + (long long)tok * DMODEL;
    const float* pr = r + (long long)tok * DMODEL;
    float v0 = pa[tid] + pr[tid];
    float v1 = pa[tid + 256] + pr[tid + 256];
    float s = v0 + v1;
    float q = v0 * v0 + v1 * v1;
    __shared__ float reds[4], redq[4];
#pragma unroll
    for (int off = 32; off; off >>= 1) {
        s += __shfl_xor(s, off, 64);
        q += __shfl_xor(q, off, 64);
    }
    int wid = tid >> 6;
    if ((tid & 63) == 0) { reds[wid] = s; redq[wid] = q; }
    __syncthreads();
    s = reds[0] + reds[1] + reds[2] + reds[3];
    q = redq[0] + redq[1] + redq[2] + redq[3];
    float mean = s * (1.f / DMODEL);
    float var = q * (1.f / DMODEL) - mean * mean;
    float rs = rsqrtf(var + 1e-5f);
    float* po = out + (long long)tok * DMODEL;
    po[tid]       = (v0 - mean) * rs * g[tid]       + bb[tid];
    po[tid + 256] = (v1 - mean) * rs * g[tid + 256] + bb[tid + 256];
}

// ---------------------------------------------------------------------------
// Decode v6: IN-PLACE over d_out (base was written in [b][t][s] layout by the
// DECODE_LAYOUT base gemm). One block per batch, 128 threads. Thread s owns
// column s: prefetches p[0..99] (its own column only), barrier, then the
// argmax chain (R9-green reduce: shfl tree + rv/ri LDS + 2 barriers, strict >,
// lowest-index tie-break) overwrites the same column. Race-free: each thread
// reads/writes only its own column; blocks touch disjoint 10000-elem regions.
// All stores clamped to [-1e38,1e38].
// ---------------------------------------------------------------------------
__global__ __launch_bounds__(128) void decode6_k(float* __restrict__ out)
{
    __shared__ float rv[2];
    __shared__ int ri[2];
    __shared__ int win;
    int b = blockIdx.x;
    int s = threadIdx.x;
    float* po = out + (long long)b * (SEQ * SEQ);

    float p[SEQ];
#pragma unroll
    for (int t = 0; t < SEQ; ++t)
        p[t] = (s < SEQ) ? clamp_finite(po[t * SEQ + s]) : MASKED_VAL;
    __syncthreads();

    bool alive = true;
#pragma unroll
    for (int t = 0; t < SEQ; ++t) {
        float val = (s < SEQ && alive) ? p[t] : MASKED_VAL;
        if (s < SEQ) po[t * SEQ + s] = val;
        float v = val;
        int ii = s;
#pragma unroll
        for (int off = 32; off; off >>= 1) {
            float ov = __shfl_down(v, off, 64);
            int oi = __shfl_down(ii, off, 64);
            if (ov > v || (ov == v && oi < ii)) { v = ov; ii = oi; }
        }
        int wid = s >> 6;
        if ((s & 63) == 0) { rv[wid] = v; ri[wid] = ii; }
        __syncthreads();
        if (s == 0) {
            float v0 = rv[0], v1 = rv[1];
            int i0 = ri[0], i1 = ri[1];
            win = (v1 > v0 || (v1 == v0 && i1 < i0)) ? i1 : i0;
        }
        __syncthreads();
        if (win == s) alive = false;
    }
}

extern "C" void kernel_launch(void* const* d_in, const int* in_sizes, int n_in,
                              void* d_out, int out_size, void* d_ws, size_t ws_size,
                              hipStream_t stream)
{
    const float* x          = (const float*)d_in[0];
    const float* ve_w1      = (const float*)d_in[1];
    const float* ve_b1      = (const float*)d_in[2];
    const float* ve_w2      = (const float*)d_in[3];
    const float* ve_b2      = (const float*)d_in[4];
    const float* pos_emb    = (const float*)d_in[5];
    const float* attn_in_w  = (const float*)d_in[6];
    const float* attn_in_b  = (const float*)d_in[7];
    const float* attn_out_w = (const float*)d_in[8];
    const float* attn_out_b = (const float*)d_in[9];
    const float* ffn_w1     = (const float*)d_in[10];
    const float* ffn_b1     = (const float*)d_in[11];
    const float* ffn_w2     = (const float*)d_in[12];
    const float* ffn_b2     = (const float*)d_in[13];
    const float* ln1_g      = (const float*)d_in[14];
    const float* ln1_b      = (const float*)d_in[15];
    const float* ln2_g      = (const float*)d_in[16];
    const float* ln2_b      = (const float*)d_in[17];
    const float* rank_emb   = (const float*)d_in[18];
    const float* qp_w       = (const float*)d_in[19];
    const float* qp_b       = (const float*)d_in[20];
    const float* kp_w       = (const float*)d_in[21];
    const float* kp_b       = (const float*)d_in[22];
    float* outp             = (float*)d_out;

    // ---- workspace plan ----
    // Persistent: qdec [100,512] (0.2MB). base lives in d_out ([b][t][s] via
    // DECODE_LAYOUT epilogue). Per-chunk (T = CB*100 tokens):
    //   r0 h -> z         : T*512
    //   r1 qkv -> mid half: T*1536
    //   r2 h1/S/tmp/tmp2/kdec : T*800
    //   r3 ao -> h2       : T*512       -> 3360 floats/token
    const size_t GUARD = 4096;
    const int plans[] = {256, 128, 64, 32, 16, 8, 4, 2, 1};
    int CB = 0;
    for (int i = 0; i < 9; ++i) {
        long long T = plans[i] * 100LL;
        size_t need = 204800 + GUARD + ((size_t)(T * 3360LL) + 4096) * 4;
        if (need <= ws_size) { CB = plans[i]; break; }
    }
    if (CB == 0) return;

    const long long T = CB * 100LL;
    char* ws = (char*)d_ws;
    float* qdec = (float*)ws;                        // [100,512]
    float* r0   = (float*)(ws + 204800 + GUARD);     // h, later z
    float* r1   = r0 + T * 512 + 1024;               // qkv, later mid-half
    float* r2   = r1 + T * 1536 + 1024;              // h1/S/tmp/tmp2/kdec
    float* r3   = r2 + T * 800 + 1024;               // ao, later h2
    const long long Z = 0;
    const int gy = (int)((T + 63) / 64);             // 64-tiles over T
    const int gym = (int)((T + 127) / 128);          // 128-tiles over T
    const int nchunk = 256 / CB;

    // q_dec = rank_emb @ qp_w^T + qp_b   (M=100,N=512,K=512) -- fp32 path
    gemm_k<false, false, false, false, false><<<dim3(8, 2, 1), 256, 0, stream>>>(
        rank_emb, qp_w, qp_b, nullptr, qdec,
        100, 512, 512, 512, 512, 512, 1, Z, Z, Z, Z, Z, Z, 1.f);

    for (int c = 0; c < nchunk; ++c) {
        const long long tok0 = (long long)c * T;

        // 1) h1 = relu(x*w1+b1) -> r2 [T,256]
        embed_h1<<<dim3((unsigned)T), dim3(256), 0, stream>>>(x + tok0, ve_w1, ve_b1, r2);

        // 2) h = h1 @ ve_w2^T + ve_b2 + pos -> r0   (MFMA, M=T,N=512,K=256)
        gemm_mfma<false, true, false><<<dim3(4, gym), 256, 0, stream>>>(
            r2, ve_w2, ve_b2, pos_emb, r0, (int)T, 512, 256, 256, 256, 512);

        // 3) qkv = h @ attn_in_w^T + attn_in_b -> r1   (MFMA, N=1536,K=512)
        gemm_mfma<false, false, false><<<dim3(12, gym), 256, 0, stream>>>(
            r0, attn_in_w, attn_in_b, nullptr, r1, (int)T, 1536, 512, 512, 512, 1536);

        // 4) S = (Q @ K^T)/8, batched over CB*8 -> r2   (fp32, M=100,N=100,K=64)
        gemm_k<false, false, false, false, false><<<dim3(2, 2, CB * 8), 256, 0, stream>>>(
            r1, r1 + 512, nullptr, nullptr, r2,
            100, 100, 64, 1536, 1536, 100,
            8, 153600LL, 64LL, 153600LL, 64LL, 80000LL, 10000LL, 0.125f);

        // 5) softmax rows of S  (T*8 rows)
        softmax_rows<<<dim3((unsigned)((T * 8 + 3) / 4)), dim3(256), 0, stream>>>(r2, (int)(T * 8));

        // 6) ao = P @ V, batched -> r3   (fp32, M=100,N=64,K=100)
        gemm_k<false, true, false, false, false><<<dim3(1, 2, CB * 8), 256, 0, stream>>>(
            r2, r1 + 1024, nullptr, nullptr, r3,
            100, 64, 100, 100, 1536, 512,
            8, 80000LL, 10000LL, 153600LL, 64LL, 51200LL, 64LL, 1.f);

        // 7) tmp = ao @ attn_out_w^T + attn_out_b -> r2   (MFMA, N=512,K=512)
        gemm_mfma<false, false, false><<<dim3(4, gym), 256, 0, stream>>>(
            r3, attn_out_w, attn_out_b, nullptr, r2, (int)T, 512, 512, 512, 512, 512);

        // 8) h2 = LN(h + tmp) -> r3
        add_ln<<<dim3((unsigned)T), dim3(256), 0, stream>>>(r0, r2, ln1_g, ln1_b, r3);

        // 9a) mid_a = relu(h2 @ W1[0:1024]^T + b1a) -> r1   (MFMA, N=1024)
        gemm_mfma<true, false, false><<<dim3(8, gym), 256, 0, stream>>>(
            r3, ffn_w1, ffn_b1, nullptr, r1, (int)T, 1024, 512, 512, 512, 1024);

        // 9b) tmp2 = mid_a @ W2[:,0:1024]^T + b2 -> r2   (MFMA, K=1024)
        gemm_mfma<false, false, false><<<dim3(4, gym), 256, 0, stream>>>(
            r1, ffn_w2, ffn_b2, nullptr, r2, (int)T, 512, 1024, 1024, 2048, 512);

        // 9c) mid_b = relu(h2 @ W1[1024:2048]^T + b1b) -> r1   (MFMA)
        gemm_mfma<true, false, false><<<dim3(8, gym), 256, 0, stream>>>(
            r3, ffn_w1 + 1024 * 512, ffn_b1 + 1024, nullptr, r1,
            (int)T, 1024, 512, 512, 512, 1024);

        // 9d) tmp2 += mid_b @ W2[:,1024:2048]^T   (MFMA, ACCUM)
        gemm_mfma<false, false, true><<<dim3(4, gym), 256, 0, stream>>>(
            r1, ffn_w2 + 1024, nullptr, nullptr, r2, (int)T, 512, 1024, 1024, 2048, 512);

        // 10) z = LN(h2 + tmp2) -> r0
        add_ln<<<dim3((unsigned)T), dim3(256), 0, stream>>>(r3, r2, ln2_g, ln2_b, r0);

        // 11) k_dec = z @ kp_w^T + kp_b -> r2   (MFMA, N=512,K=512)
        gemm_mfma<false, false, false><<<dim3(4, gym), 256, 0, stream>>>(
            r0, kp_w, kp_b, nullptr, r2, (int)T, 512, 512, 512, 512, 512);

        // 12) base (this chunk) = q_dec @ k_dec^T -> d_out[b][t][s] layout
        //     (fp32 path, M=100, N=T, DECODE_LAYOUT epilogue)
        gemm_k<false, false, false, false, true><<<dim3(gy, 2, 1), 256, 0, stream>>>(
            qdec, r2, nullptr, nullptr, outp + (long long)c * CB * (SEQ * SEQ),
            100, (int)T, 512, 512, 512, 0, 1, Z, Z, Z, Z, Z, Z, 1.f);
    }

    // 13) single in-place masked-argmax decode over all 256 batches
    decode6_k<<<dim3(256), dim3(128), 0, stream>>>(outp);
}